// Round 1
// baseline (203.618 us; speedup 1.0000x reference)
//
#include <hip/hip_runtime.h>
#include <hip/hip_bf16.h>

// Difference3DCostVolume: cost[b,c,d,h,w] = l[b,c,h,w] - r[b,c,h,w-d] (w>=d), else 1.0
// Shapes: B=4, C=32, H=96, W=312, D=48. Output layout [B,C,D,H,W] float32.
// Write-bound: 736 MB out vs 30.7 MB in. One block per (b,c,h); LDS-stage the
// two 312-float rows, emit 48 output rows as coalesced float4 stores.

#define BB 4
#define CC 32
#define HH 96
#define WW 312
#define DD 48
#define W4 (WW / 4)          // 78
#define ITEMS (DD * W4)      // 3744
#define NBLOCKS (BB * CC * HH)  // 12288

__global__ __launch_bounds__(256) void cost_volume_kernel(
    const float* __restrict__ l, const float* __restrict__ r,
    float* __restrict__ out) {
    const int bch = blockIdx.x;          // = (b*CC + c)*HH + h
    const int tid = threadIdx.x;

    __shared__ float ls[WW];
    __shared__ float rs[WW];

    // Stage the two rows (312 floats each) into LDS, vectorized.
    {
        const float4* lrow = reinterpret_cast<const float4*>(l + (size_t)bch * WW);
        const float4* rrow = reinterpret_cast<const float4*>(r + (size_t)bch * WW);
        float4* ls4 = reinterpret_cast<float4*>(ls);
        float4* rs4 = reinterpret_cast<float4*>(rs);
        for (int i = tid; i < W4; i += 256) {
            ls4[i] = lrow[i];
            rs4[i] = rrow[i];
        }
    }
    __syncthreads();

    // Output base for this (b,c,·,h,·): flat = ((bc*DD + d)*HH + h)*WW + w
    const int h = bch % HH;
    const int bc = bch / HH;
    float* obase = out + ((size_t)bc * DD * HH + h) * (size_t)WW;

    // Each float4 item covers output (d, w4): w = 4*w4.
    for (int item = tid; item < ITEMS; item += 256) {
        const int d = item / W4;               // magic-div by 78
        const int w4 = item - d * W4;
        const int w = w4 * 4;
        float4 v;
        float* vp = &v.x;
        #pragma unroll
        for (int j = 0; j < 4; ++j) {
            const int wj = w + j;
            vp[j] = (wj >= d) ? (ls[wj] - rs[wj - d]) : 1.0f;
        }
        *reinterpret_cast<float4*>(obase + (size_t)d * (HH * WW) + w) = v;
    }
}

extern "C" void kernel_launch(void* const* d_in, const int* in_sizes, int n_in,
                              void* d_out, int out_size, void* d_ws, size_t ws_size,
                              hipStream_t stream) {
    const float* l = (const float*)d_in[0];
    const float* r = (const float*)d_in[1];
    float* out = (float*)d_out;
    cost_volume_kernel<<<dim3(NBLOCKS), dim3(256), 0, stream>>>(l, r, out);
}

// Round 2
// 170.542 us; speedup vs baseline: 1.1940x; 1.1940x over previous
//
#include <hip/hip_runtime.h>
#include <hip/hip_bf16.h>

// Difference3DCostVolume: cost[b,c,d,h,w] = l[b,c,h,w] - r[b,c,h,w-d] (w>=d), else 1.0
// Shapes: B=4, C=32, H=96, W=312, D=48. Output [B,C,D,H,W] f32 = 736 MB -> write-bound.
//
// R1 design:
//  - one block per (b,c,h-pair): 2 rows x 2496 B = 39 full 64B lines, line-aligned,
//    so every store extent is whole-line (no masked-write overhead at boundaries).
//  - LDS: ls rows + 4 byte-rotated copies of r rows (rsr[r][m] = rs[m-r]) so both
//    the l-read and the shifted r-read are aligned conflict-free ds_read_b128:
//    rs[w-d .. w+3-d] == rsr[d&3][ w4-(d>>2) ] (float4).

#define BB 4
#define CC 32
#define HH 96
#define WW 312
#define DD 48
#define W4 (WW / 4)            // 78
#define HPAIRS (HH / 2)        // 48
#define RLEN 320               // padded length of rotated copies (>= WW+4, 16B-mult)
#define ITEMS (DD * 2 * W4)    // 7488 float4 stores per block
#define NBLOCKS (BB * CC * HPAIRS)  // 6144

__global__ __launch_bounds__(256) void cost_volume_kernel(
    const float* __restrict__ l, const float* __restrict__ r,
    float* __restrict__ out) {
    const int blk = blockIdx.x;
    const int tid = threadIdx.x;
    const int hp = blk % HPAIRS;
    const int bc = blk / HPAIRS;
    const int h0 = hp * 2;

    __shared__ float ls[2][WW];         // 2496 B
    __shared__ float rsr[2][4][RLEN];   // 10240 B : rsr[hh][r][m] = r_row[hh][m-r]

    const float* lbase = l + ((size_t)bc * HH + h0) * WW;
    const float* rbase = r + ((size_t)bc * HH + h0) * WW;

    // Stage ls as float4 (156 vec4 loads/stores).
    {
        const float4* l4 = reinterpret_cast<const float4*>(lbase);
        for (int i = tid; i < 2 * W4; i += 256) {
            const int hh = (i >= W4) ? 1 : 0;
            const int w4 = i - hh * W4;
            reinterpret_cast<float4*>(ls[hh])[w4] = l4[hh * W4 + w4];
        }
    }
    // Stage 4 rotated copies of each r row (scalar, consecutive -> conflict-free).
    for (int i = tid; i < 2 * 4 * RLEN; i += 256) {
        const int hh = i / (4 * RLEN);
        const int rest = i - hh * (4 * RLEN);
        const int rr = rest / RLEN;
        const int m = rest - rr * RLEN;
        const int src = m - rr;
        rsr[hh][rr][m] = (src >= 0 && src < WW) ? rbase[hh * WW + src] : 0.0f;
    }
    __syncthreads();

    // Output base for this (b,c,h0): flat = ((bc*DD + d)*HH + h0 + hh)*WW + w
    float* obase = out + ((size_t)bc * DD * HH + h0) * (size_t)WW;

    for (int item = tid; item < ITEMS; item += 256) {
        const int t2 = item / W4;        // 0..95  (d*2 + hh)
        const int w4 = item - t2 * W4;   // 0..77
        const int d = t2 >> 1;
        const int hh = t2 & 1;
        const int k = w4 - (d >> 2);
        const int kk = (k < 0) ? 0 : k;  // clamped; clamped lanes are all-invalid
        const int w = w4 * 4;

        const float4 a = *reinterpret_cast<const float4*>(&ls[hh][w]);
        const float4 b = *reinterpret_cast<const float4*>(&rsr[hh][d & 3][kk * 4]);

        float4 v;
        v.x = (w     >= d) ? a.x - b.x : 1.0f;
        v.y = (w + 1 >= d) ? a.y - b.y : 1.0f;
        v.z = (w + 2 >= d) ? a.z - b.z : 1.0f;
        v.w = (w + 3 >= d) ? a.w - b.w : 1.0f;

        *reinterpret_cast<float4*>(obase + ((size_t)d * HH + hh) * WW + w) = v;
    }
}

extern "C" void kernel_launch(void* const* d_in, const int* in_sizes, int n_in,
                              void* d_out, int out_size, void* d_ws, size_t ws_size,
                              hipStream_t stream) {
    const float* l = (const float*)d_in[0];
    const float* r = (const float*)d_in[1];
    float* out = (float*)d_out;
    cost_volume_kernel<<<dim3(NBLOCKS), dim3(256), 0, stream>>>(l, r, out);
}